// Round 2
// baseline (512.292 us; speedup 1.0000x reference)
//
#include <hip/hip_runtime.h>

// Bidirectional LSTM, B=256, T=1024, V=6, D=64, U=64; out = last-step
// concat(h_f, h_b) @ Wd + bd, shape (B,1).
// Reductions: backward dir = ONE step from h0=0 (Wr_b dead); V=6 -> xproj is
// a 6-entry table; mask = 6-bit scalar.
// R12 (4 waves + dpp reduce + per-step barrier): 296us (barrier+reduce chain
// ~500cyc/step overhead on ~120cyc issue).
// R13 (single wave, ARRAY weights): 456us REGRESSED. VGPR=88 proves wh[4][32]
// + H[32] went to scratch (needs >=160 regs); ~128 scratch reloads/step.
// R14: same single-wave structure, ALL hot-loop arrays replaced by NAMED
// registers (R12's proven DECLH pattern scaled to 128 v2h weights + H0..H31).
// No barriers in the 1024-step loop (same-wave in-order DS makes the h
// ds_write -> broadcast ds_read safe; double-buffered anyway). Each lane owns
// unit l: 4 full gate columns, 128 dot2/step, own activations, own c/h.
// h exchange = 1 ds_write_b16 + 8 broadcast ds_read_b128 (conflict-free).

constexpr int kB = 256;
constexpr int kT = 1024;
constexpr int kV = 6;
constexpr int kD = 64;
constexpr int kU = 64;
constexpr int kG = 256; // 4*U gate columns

#define LOG2E 1.44269504f

typedef _Float16 v2h __attribute__((ext_vector_type(2)));

__device__ __forceinline__ float fast_rcp(float x) { return __builtin_amdgcn_rcpf(x); }
__device__ __forceinline__ float exp2_f(float x)   { return __builtin_amdgcn_exp2f(x); }
__device__ __forceinline__ float sig_f(float z)  { return fast_rcp(1.0f + exp2_f(-LOG2E * z)); }
__device__ __forceinline__ float tanh_f(float z) { return 2.0f * fast_rcp(1.0f + exp2_f(-2.0f * LOG2E * z)) - 1.0f; }

__device__ __forceinline__ v2h as_v2h(float x) { return __builtin_bit_cast(v2h, x); }

__global__ __launch_bounds__(64, 1) void bilstm_last_kernel(
    const int*   __restrict__ tokens, // (B,T)
    const float* __restrict__ emb,    // (6,64)
    const float* __restrict__ Wk_f,   // (64,256)
    const float* __restrict__ Wr_f,   // (64,256)
    const float* __restrict__ b_f,    // (256)
    const float* __restrict__ Wk_b,   // (64,256)
    const float* __restrict__ b_b,    // (256)
    const float* __restrict__ Wd,     // (128)
    const float* __restrict__ bd,     // (1)
    float*       __restrict__ out)    // (B)
{
    __shared__ float s_emb[kV * kD];
    __shared__ float __align__(16) s_projPP[kV * kU * 4]; // [v][u][gate] f32
    __shared__ int   __align__(16) s_tok[kT];
    __shared__ _Float16 __align__(16) s_hh[2][kU];        // double-buffered h (f16)

    const int b = blockIdx.x;
    const int l = threadIdx.x;   // lane 0..63 == unit id

    // ---- stage emb + tokens (single wave: no barriers needed anywhere) ----
#pragma unroll
    for (int i = 0; i < kV * kD; i += 64) s_emb[i + l] = emb[i + l];
    {
        const int4* src = (const int4*)(tokens + b * kT);
        int4* dst = (int4*)s_tok;
#pragma unroll
        for (int i = 0; i < 4; ++i) dst[64 * i + l] = src[64 * i + l];
    }
    s_hh[0][l] = (_Float16)0.f;
    s_hh[1][l] = (_Float16)0.f;

    // ---- 6-bit mask, scalarized: bit v = any(emb[v][:] != 0) ----
    unsigned int mbv = 0;
#pragma unroll
    for (int v = 0; v < kV; ++v) {
        const unsigned long long bb = __ballot(s_emb[v * kD + l] != 0.0f);
        mbv |= (bb != 0ull) ? (1u << v) : 0u;
    }
    const unsigned int smb = __builtin_amdgcn_readfirstlane(mbv);

    const int tokL = __builtin_amdgcn_readfirstlane(s_tok[kT - 1]);

    // ---- proj tables: lane l computes columns g*64+l, g=0..3, all 6 tokens,
    //      plus the backward proj at the last token ----
    float af[kV][4];
    float ab4[4];
#pragma unroll
    for (int g = 0; g < 4; ++g) {
        const float bf = b_f[g * kU + l];
#pragma unroll
        for (int v = 0; v < kV; ++v) af[v][g] = bf;
        ab4[g] = b_b[g * kU + l];
    }
#pragma unroll 4
    for (int d = 0; d < kD; ++d) {
        const float e0 = s_emb[0 * kD + d], e1 = s_emb[1 * kD + d];
        const float e2 = s_emb[2 * kD + d], e3 = s_emb[3 * kD + d];
        const float e4 = s_emb[4 * kD + d], e5 = s_emb[5 * kD + d];
        const float eb = s_emb[tokL * kD + d];
#pragma unroll
        for (int g = 0; g < 4; ++g) {
            const float wkf = Wk_f[d * kG + g * kU + l];
            const float wkb = Wk_b[d * kG + g * kU + l];
            af[0][g] = fmaf(e0, wkf, af[0][g]);
            af[1][g] = fmaf(e1, wkf, af[1][g]);
            af[2][g] = fmaf(e2, wkf, af[2][g]);
            af[3][g] = fmaf(e3, wkf, af[3][g]);
            af[4][g] = fmaf(e4, wkf, af[4][g]);
            af[5][g] = fmaf(e5, wkf, af[5][g]);
            ab4[g]   = fmaf(eb, wkb, ab4[g]);
        }
    }
#pragma unroll
    for (int v = 0; v < kV; ++v) {
        float4 t4;
        t4.x = af[v][0]; t4.y = af[v][1]; t4.z = af[v][2]; t4.w = af[v][3];
        ((float4*)s_projPP)[v * kU + l] = t4;
    }

    // ---- backward single step (per-lane, no LDS): c0=0 -> f dead ----
    float hb_val;
    {
        const float ib = sig_f(ab4[0]);
        const float gb = tanh_f(ab4[2]);
        const float ob = sig_f(ab4[3]);
        const float cb = ib * gb;
        const float hb = ob * tanh_f(cb);
        hb_val = ((smb >> tokL) & 1) ? hb : 0.0f;
    }

    // ---- recurrent weights: lane l holds full columns g*64+l as f16 pairs,
    //      as 128 NAMED v2h variables (arrays spill to scratch - R13 lesson) ----
#define DECLW(g, p)                                                           \
    v2h wh##g##_##p;                                                          \
    wh##g##_##p.x = (_Float16)Wr_f[(2 * (p) + 0) * kG + (g) * kU + l];        \
    wh##g##_##p.y = (_Float16)Wr_f[(2 * (p) + 1) * kG + (g) * kU + l];
#define DECLW_G(g)                                                            \
    DECLW(g, 0)  DECLW(g, 1)  DECLW(g, 2)  DECLW(g, 3)                        \
    DECLW(g, 4)  DECLW(g, 5)  DECLW(g, 6)  DECLW(g, 7)                        \
    DECLW(g, 8)  DECLW(g, 9)  DECLW(g, 10) DECLW(g, 11)                       \
    DECLW(g, 12) DECLW(g, 13) DECLW(g, 14) DECLW(g, 15)                       \
    DECLW(g, 16) DECLW(g, 17) DECLW(g, 18) DECLW(g, 19)                       \
    DECLW(g, 20) DECLW(g, 21) DECLW(g, 22) DECLW(g, 23)                       \
    DECLW(g, 24) DECLW(g, 25) DECLW(g, 26) DECLW(g, 27)                       \
    DECLW(g, 28) DECLW(g, 29) DECLW(g, 30) DECLW(g, 31)
    DECLW_G(0) DECLW_G(1) DECLW_G(2) DECLW_G(3)
#undef DECLW_G
#undef DECLW

    float c = 0.0f, hreg = 0.0f;

    // ---- scalar token pipeline, depth 2 ----
    int stok0 = __builtin_amdgcn_readfirstlane(s_tok[0]);
    float4 zcur = ((const float4*)s_projPP)[stok0 * kU + l];
    int mskc = (smb >> stok0) & 1;
    int stokA = __builtin_amdgcn_readfirstlane(s_tok[1]);

    // per gate: 32 dot2 as 2 interleaved chains of depth 16, seeded with proj
#define DOTG(g, seed, zout)                                                   \
    {                                                                         \
        float pa = __builtin_amdgcn_fdot2(H0,  wh##g##_0,  (seed), false);    \
        float pb = __builtin_amdgcn_fdot2(H1,  wh##g##_1,  0.0f,   false);    \
        pa = __builtin_amdgcn_fdot2(H2,  wh##g##_2,  pa, false);              \
        pb = __builtin_amdgcn_fdot2(H3,  wh##g##_3,  pb, false);              \
        pa = __builtin_amdgcn_fdot2(H4,  wh##g##_4,  pa, false);              \
        pb = __builtin_amdgcn_fdot2(H5,  wh##g##_5,  pb, false);              \
        pa = __builtin_amdgcn_fdot2(H6,  wh##g##_6,  pa, false);              \
        pb = __builtin_amdgcn_fdot2(H7,  wh##g##_7,  pb, false);              \
        pa = __builtin_amdgcn_fdot2(H8,  wh##g##_8,  pa, false);              \
        pb = __builtin_amdgcn_fdot2(H9,  wh##g##_9,  pb, false);              \
        pa = __builtin_amdgcn_fdot2(H10, wh##g##_10, pa, false);              \
        pb = __builtin_amdgcn_fdot2(H11, wh##g##_11, pb, false);              \
        pa = __builtin_amdgcn_fdot2(H12, wh##g##_12, pa, false);              \
        pb = __builtin_amdgcn_fdot2(H13, wh##g##_13, pb, false);              \
        pa = __builtin_amdgcn_fdot2(H14, wh##g##_14, pa, false);              \
        pb = __builtin_amdgcn_fdot2(H15, wh##g##_15, pb, false);              \
        pa = __builtin_amdgcn_fdot2(H16, wh##g##_16, pa, false);              \
        pb = __builtin_amdgcn_fdot2(H17, wh##g##_17, pb, false);              \
        pa = __builtin_amdgcn_fdot2(H18, wh##g##_18, pa, false);              \
        pb = __builtin_amdgcn_fdot2(H19, wh##g##_19, pb, false);              \
        pa = __builtin_amdgcn_fdot2(H20, wh##g##_20, pa, false);              \
        pb = __builtin_amdgcn_fdot2(H21, wh##g##_21, pb, false);              \
        pa = __builtin_amdgcn_fdot2(H22, wh##g##_22, pa, false);              \
        pb = __builtin_amdgcn_fdot2(H23, wh##g##_23, pb, false);              \
        pa = __builtin_amdgcn_fdot2(H24, wh##g##_24, pa, false);              \
        pb = __builtin_amdgcn_fdot2(H25, wh##g##_25, pb, false);              \
        pa = __builtin_amdgcn_fdot2(H26, wh##g##_26, pa, false);              \
        pb = __builtin_amdgcn_fdot2(H27, wh##g##_27, pb, false);              \
        pa = __builtin_amdgcn_fdot2(H28, wh##g##_28, pa, false);              \
        pb = __builtin_amdgcn_fdot2(H29, wh##g##_29, pb, false);              \
        pa = __builtin_amdgcn_fdot2(H30, wh##g##_30, pa, false);              \
        pb = __builtin_amdgcn_fdot2(H31, wh##g##_31, pb, false);              \
        zout = pa + pb;                                                       \
    }

#define STEP(RP, WP, TT)                                                      \
    {                                                                         \
        /* h broadcast: all lanes read the same 128B -> conflict-free */      \
        const float4* hp = (const float4*)s_hh[RP];                           \
        const float4 hv0 = hp[0], hv1 = hp[1], hv2 = hp[2], hv3 = hp[3];      \
        const float4 hv4 = hp[4], hv5 = hp[5], hv6 = hp[6], hv7 = hp[7];      \
        /* prefetches queued behind h; consumed next step */                  \
        const int   vtokB = s_tok[((TT) + 2) & (kT - 1)];                     \
        const float4 znext = ((const float4*)s_projPP)[stokA * kU + l];       \
        const int   mskn = (int)((smb >> stokA) & 1);                         \
        const v2h H0  = as_v2h(hv0.x), H1  = as_v2h(hv0.y);                   \
        const v2h H2  = as_v2h(hv0.z), H3  = as_v2h(hv0.w);                   \
        const v2h H4  = as_v2h(hv1.x), H5  = as_v2h(hv1.y);                   \
        const v2h H6  = as_v2h(hv1.z), H7  = as_v2h(hv1.w);                   \
        const v2h H8  = as_v2h(hv2.x), H9  = as_v2h(hv2.y);                   \
        const v2h H10 = as_v2h(hv2.z), H11 = as_v2h(hv2.w);                   \
        const v2h H12 = as_v2h(hv3.x), H13 = as_v2h(hv3.y);                   \
        const v2h H14 = as_v2h(hv3.z), H15 = as_v2h(hv3.w);                   \
        const v2h H16 = as_v2h(hv4.x), H17 = as_v2h(hv4.y);                   \
        const v2h H18 = as_v2h(hv4.z), H19 = as_v2h(hv4.w);                   \
        const v2h H20 = as_v2h(hv5.x), H21 = as_v2h(hv5.y);                   \
        const v2h H22 = as_v2h(hv5.z), H23 = as_v2h(hv5.w);                   \
        const v2h H24 = as_v2h(hv6.x), H25 = as_v2h(hv6.y);                   \
        const v2h H26 = as_v2h(hv6.z), H27 = as_v2h(hv6.w);                   \
        const v2h H28 = as_v2h(hv7.x), H29 = as_v2h(hv7.y);                   \
        const v2h H30 = as_v2h(hv7.z), H31 = as_v2h(hv7.w);                   \
        float zi, zf, zg, zo;                                                 \
        DOTG(0, zcur.x, zi)                                                   \
        DOTG(1, zcur.y, zf)                                                   \
        DOTG(2, zcur.z, zg)                                                   \
        DOTG(3, zcur.w, zo)                                                   \
        const float ai  = sig_f(zi);                                          \
        const float afv = sig_f(zf);                                          \
        const float ag  = tanh_f(zg);                                         \
        const float ao  = sig_f(zo);                                          \
        const float cn = fmaf(afv, c, ai * ag);                               \
        const float hn = ao * tanh_f(cn);                                     \
        if (mskc) { c = cn; hreg = hn; }   /* uniform branch */               \
        s_hh[WP][l] = (_Float16)hreg;                                         \
        zcur = znext; mskc = mskn;                                            \
        stokA = __builtin_amdgcn_readfirstlane(vtokB);                        \
    }

    for (int t = 0; t < kT; t += 2) {
        STEP(0, 1, t)
        STEP(1, 0, t + 1)
    }
#undef STEP
#undef DOTG

    // ---- epilogue: lane l holds exact f32 h_f[l] and h_b[l] ----
    float v = hreg * Wd[l] + hb_val * Wd[kU + l];
#pragma unroll
    for (int off = 32; off > 0; off >>= 1) v += __shfl_down(v, off, 64);
    if (l == 0) out[b] = v + bd[0];
}

extern "C" void kernel_launch(void* const* d_in, const int* in_sizes, int n_in,
                              void* d_out, int out_size, void* d_ws, size_t ws_size,
                              hipStream_t stream) {
    const int*   tokens = (const int*)d_in[0];
    const float* emb    = (const float*)d_in[1];
    const float* Wk_f   = (const float*)d_in[2];
    const float* Wr_f   = (const float*)d_in[3];
    const float* b_f    = (const float*)d_in[4];
    const float* Wk_b   = (const float*)d_in[5];
    // d_in[6] = Wr_b: unused (backward runs one step from h0=0)
    const float* b_b    = (const float*)d_in[7];
    const float* Wd     = (const float*)d_in[8];
    const float* bd     = (const float*)d_in[9];
    float* out = (float*)d_out;

    bilstm_last_kernel<<<kB, 64, 0, stream>>>(
        tokens, emb, Wk_f, Wr_f, b_f, Wk_b, b_b, Wd, bd, out);
}

// Round 3
// 458.011 us; speedup vs baseline: 1.1185x; 1.1185x over previous
//
#include <hip/hip_runtime.h>

// Bidirectional LSTM, B=256, T=1024, V=6, D=64, U=64; out = last-step
// concat(h_f, h_b) @ Wd + bd, shape (B,1).
// Reductions: backward dir = ONE step from h0=0 (Wr_b dead); V=6 -> xproj is
// a 6-entry table; mask = 6-bit scalar.
// R12 (4 waves + dpp reduce + per-step barrier): 296us.
// R13/R14 (single wave, 128 v2h weights resident): 460us REGRESSED, VGPR=88
//   in BOTH -> allocator spilled weights to scratch (~256 reloads/step). The
//   named-vs-array rewrite changed nothing: constant-indexed arrays already
//   promote; the RA's occupancy TARGET was the bug, not the source form.
// R15: R14 + __attribute__((amdgpu_waves_per_eu(1,1))). launch_bounds' 2nd
//   arg only sets a minimum (VGPR ceiling); the scheduler still targeted ~5-6
//   waves/EU and spilled down to 88 regs. min=max=1 gives RA the full 512-reg
//   file; we launch exactly 1 wave/CU so extra occupancy is pure waste.
//   #pragma unroll 1 keeps the 2-STEP macro body from further unrolling.
// Structure: lane l owns unit l: 4 full gate columns (128 f16-pair VGPRs),
// 128 dot2/step, own activations, own c/h. No barriers in the 1024-step loop
// (same-wave in-order DS). h exchange = ds_write_b16 + 8 broadcast
// ds_read_b128 (conflict-free).

constexpr int kB = 256;
constexpr int kT = 1024;
constexpr int kV = 6;
constexpr int kD = 64;
constexpr int kU = 64;
constexpr int kG = 256; // 4*U gate columns

#define LOG2E 1.44269504f

typedef _Float16 v2h __attribute__((ext_vector_type(2)));

__device__ __forceinline__ float fast_rcp(float x) { return __builtin_amdgcn_rcpf(x); }
__device__ __forceinline__ float exp2_f(float x)   { return __builtin_amdgcn_exp2f(x); }
__device__ __forceinline__ float sig_f(float z)  { return fast_rcp(1.0f + exp2_f(-LOG2E * z)); }
__device__ __forceinline__ float tanh_f(float z) { return 2.0f * fast_rcp(1.0f + exp2_f(-2.0f * LOG2E * z)) - 1.0f; }

__device__ __forceinline__ v2h as_v2h(float x) { return __builtin_bit_cast(v2h, x); }

__global__ __launch_bounds__(64)
__attribute__((amdgpu_waves_per_eu(1, 1)))
void bilstm_last_kernel(
    const int*   __restrict__ tokens, // (B,T)
    const float* __restrict__ emb,    // (6,64)
    const float* __restrict__ Wk_f,   // (64,256)
    const float* __restrict__ Wr_f,   // (64,256)
    const float* __restrict__ b_f,    // (256)
    const float* __restrict__ Wk_b,   // (64,256)
    const float* __restrict__ b_b,    // (256)
    const float* __restrict__ Wd,     // (128)
    const float* __restrict__ bd,     // (1)
    float*       __restrict__ out)    // (B)
{
    __shared__ float s_emb[kV * kD];
    __shared__ float __align__(16) s_projPP[kV * kU * 4]; // [v][u][gate] f32
    __shared__ int   __align__(16) s_tok[kT];
    __shared__ _Float16 __align__(16) s_hh[2][kU];        // double-buffered h (f16)

    const int b = blockIdx.x;
    const int l = threadIdx.x;   // lane 0..63 == unit id

    // ---- stage emb + tokens (single wave: no barriers needed anywhere) ----
#pragma unroll
    for (int i = 0; i < kV * kD; i += 64) s_emb[i + l] = emb[i + l];
    {
        const int4* src = (const int4*)(tokens + b * kT);
        int4* dst = (int4*)s_tok;
#pragma unroll
        for (int i = 0; i < 4; ++i) dst[64 * i + l] = src[64 * i + l];
    }
    s_hh[0][l] = (_Float16)0.f;
    s_hh[1][l] = (_Float16)0.f;

    // ---- 6-bit mask, scalarized: bit v = any(emb[v][:] != 0) ----
    unsigned int mbv = 0;
#pragma unroll
    for (int v = 0; v < kV; ++v) {
        const unsigned long long bb = __ballot(s_emb[v * kD + l] != 0.0f);
        mbv |= (bb != 0ull) ? (1u << v) : 0u;
    }
    const unsigned int smb = __builtin_amdgcn_readfirstlane(mbv);

    const int tokL = __builtin_amdgcn_readfirstlane(s_tok[kT - 1]);

    // ---- proj tables: lane l computes columns g*64+l, g=0..3, all 6 tokens,
    //      plus the backward proj at the last token ----
    float af[kV][4];
    float ab4[4];
#pragma unroll
    for (int g = 0; g < 4; ++g) {
        const float bf = b_f[g * kU + l];
#pragma unroll
        for (int v = 0; v < kV; ++v) af[v][g] = bf;
        ab4[g] = b_b[g * kU + l];
    }
#pragma unroll 4
    for (int d = 0; d < kD; ++d) {
        const float e0 = s_emb[0 * kD + d], e1 = s_emb[1 * kD + d];
        const float e2 = s_emb[2 * kD + d], e3 = s_emb[3 * kD + d];
        const float e4 = s_emb[4 * kD + d], e5 = s_emb[5 * kD + d];
        const float eb = s_emb[tokL * kD + d];
#pragma unroll
        for (int g = 0; g < 4; ++g) {
            const float wkf = Wk_f[d * kG + g * kU + l];
            const float wkb = Wk_b[d * kG + g * kU + l];
            af[0][g] = fmaf(e0, wkf, af[0][g]);
            af[1][g] = fmaf(e1, wkf, af[1][g]);
            af[2][g] = fmaf(e2, wkf, af[2][g]);
            af[3][g] = fmaf(e3, wkf, af[3][g]);
            af[4][g] = fmaf(e4, wkf, af[4][g]);
            af[5][g] = fmaf(e5, wkf, af[5][g]);
            ab4[g]   = fmaf(eb, wkb, ab4[g]);
        }
    }
#pragma unroll
    for (int v = 0; v < kV; ++v) {
        float4 t4;
        t4.x = af[v][0]; t4.y = af[v][1]; t4.z = af[v][2]; t4.w = af[v][3];
        ((float4*)s_projPP)[v * kU + l] = t4;
    }

    // ---- backward single step (per-lane, no LDS): c0=0 -> f dead ----
    float hb_val;
    {
        const float ib = sig_f(ab4[0]);
        const float gb = tanh_f(ab4[2]);
        const float ob = sig_f(ab4[3]);
        const float cb = ib * gb;
        const float hb = ob * tanh_f(cb);
        hb_val = ((smb >> tokL) & 1) ? hb : 0.0f;
    }

    // ---- recurrent weights: lane l holds full columns g*64+l as f16 pairs,
    //      128 named v2h (needs waves_per_eu(1,1) to stay in registers) ----
#define DECLW(g, p)                                                           \
    v2h wh##g##_##p;                                                          \
    wh##g##_##p.x = (_Float16)Wr_f[(2 * (p) + 0) * kG + (g) * kU + l];        \
    wh##g##_##p.y = (_Float16)Wr_f[(2 * (p) + 1) * kG + (g) * kU + l];
#define DECLW_G(g)                                                            \
    DECLW(g, 0)  DECLW(g, 1)  DECLW(g, 2)  DECLW(g, 3)                        \
    DECLW(g, 4)  DECLW(g, 5)  DECLW(g, 6)  DECLW(g, 7)                        \
    DECLW(g, 8)  DECLW(g, 9)  DECLW(g, 10) DECLW(g, 11)                       \
    DECLW(g, 12) DECLW(g, 13) DECLW(g, 14) DECLW(g, 15)                       \
    DECLW(g, 16) DECLW(g, 17) DECLW(g, 18) DECLW(g, 19)                       \
    DECLW(g, 20) DECLW(g, 21) DECLW(g, 22) DECLW(g, 23)                       \
    DECLW(g, 24) DECLW(g, 25) DECLW(g, 26) DECLW(g, 27)                       \
    DECLW(g, 28) DECLW(g, 29) DECLW(g, 30) DECLW(g, 31)
    DECLW_G(0) DECLW_G(1) DECLW_G(2) DECLW_G(3)
#undef DECLW_G
#undef DECLW

    float c = 0.0f, hreg = 0.0f;

    // ---- scalar token pipeline, depth 2 ----
    int stok0 = __builtin_amdgcn_readfirstlane(s_tok[0]);
    float4 zcur = ((const float4*)s_projPP)[stok0 * kU + l];
    int mskc = (smb >> stok0) & 1;
    int stokA = __builtin_amdgcn_readfirstlane(s_tok[1]);

    // per gate: 32 dot2 as 2 interleaved chains of depth 16, seeded with proj
#define DOTG(g, seed, zout)                                                   \
    {                                                                         \
        float pa = __builtin_amdgcn_fdot2(H0,  wh##g##_0,  (seed), false);    \
        float pb = __builtin_amdgcn_fdot2(H1,  wh##g##_1,  0.0f,   false);    \
        pa = __builtin_amdgcn_fdot2(H2,  wh##g##_2,  pa, false);              \
        pb = __builtin_amdgcn_fdot2(H3,  wh##g##_3,  pb, false);              \
        pa = __builtin_amdgcn_fdot2(H4,  wh##g##_4,  pa, false);              \
        pb = __builtin_amdgcn_fdot2(H5,  wh##g##_5,  pb, false);              \
        pa = __builtin_amdgcn_fdot2(H6,  wh##g##_6,  pa, false);              \
        pb = __builtin_amdgcn_fdot2(H7,  wh##g##_7,  pb, false);              \
        pa = __builtin_amdgcn_fdot2(H8,  wh##g##_8,  pa, false);              \
        pb = __builtin_amdgcn_fdot2(H9,  wh##g##_9,  pb, false);              \
        pa = __builtin_amdgcn_fdot2(H10, wh##g##_10, pa, false);              \
        pb = __builtin_amdgcn_fdot2(H11, wh##g##_11, pb, false);              \
        pa = __builtin_amdgcn_fdot2(H12, wh##g##_12, pa, false);              \
        pb = __builtin_amdgcn_fdot2(H13, wh##g##_13, pb, false);              \
        pa = __builtin_amdgcn_fdot2(H14, wh##g##_14, pa, false);              \
        pb = __builtin_amdgcn_fdot2(H15, wh##g##_15, pb, false);              \
        pa = __builtin_amdgcn_fdot2(H16, wh##g##_16, pa, false);              \
        pb = __builtin_amdgcn_fdot2(H17, wh##g##_17, pb, false);              \
        pa = __builtin_amdgcn_fdot2(H18, wh##g##_18, pa, false);              \
        pb = __builtin_amdgcn_fdot2(H19, wh##g##_19, pb, false);              \
        pa = __builtin_amdgcn_fdot2(H20, wh##g##_20, pa, false);              \
        pb = __builtin_amdgcn_fdot2(H21, wh##g##_21, pb, false);              \
        pa = __builtin_amdgcn_fdot2(H22, wh##g##_22, pa, false);              \
        pb = __builtin_amdgcn_fdot2(H23, wh##g##_23, pb, false);              \
        pa = __builtin_amdgcn_fdot2(H24, wh##g##_24, pa, false);              \
        pb = __builtin_amdgcn_fdot2(H25, wh##g##_25, pb, false);              \
        pa = __builtin_amdgcn_fdot2(H26, wh##g##_26, pa, false);              \
        pb = __builtin_amdgcn_fdot2(H27, wh##g##_27, pb, false);              \
        pa = __builtin_amdgcn_fdot2(H28, wh##g##_28, pa, false);              \
        pb = __builtin_amdgcn_fdot2(H29, wh##g##_29, pb, false);              \
        pa = __builtin_amdgcn_fdot2(H30, wh##g##_30, pa, false);              \
        pb = __builtin_amdgcn_fdot2(H31, wh##g##_31, pb, false);              \
        zout = pa + pb;                                                       \
    }

#define STEP(RP, WP, TT)                                                      \
    {                                                                         \
        /* h broadcast: all lanes read the same 128B -> conflict-free */      \
        const float4* hp = (const float4*)s_hh[RP];                           \
        const float4 hv0 = hp[0], hv1 = hp[1], hv2 = hp[2], hv3 = hp[3];      \
        const float4 hv4 = hp[4], hv5 = hp[5], hv6 = hp[6], hv7 = hp[7];      \
        /* prefetches queued behind h; consumed next step */                  \
        const int   vtokB = s_tok[((TT) + 2) & (kT - 1)];                     \
        const float4 znext = ((const float4*)s_projPP)[stokA * kU + l];       \
        const int   mskn = (int)((smb >> stokA) & 1);                         \
        const v2h H0  = as_v2h(hv0.x), H1  = as_v2h(hv0.y);                   \
        const v2h H2  = as_v2h(hv0.z), H3  = as_v2h(hv0.w);                   \
        const v2h H4  = as_v2h(hv1.x), H5  = as_v2h(hv1.y);                   \
        const v2h H6  = as_v2h(hv1.z), H7  = as_v2h(hv1.w);                   \
        const v2h H8  = as_v2h(hv2.x), H9  = as_v2h(hv2.y);                   \
        const v2h H10 = as_v2h(hv2.z), H11 = as_v2h(hv2.w);                   \
        const v2h H12 = as_v2h(hv3.x), H13 = as_v2h(hv3.y);                   \
        const v2h H14 = as_v2h(hv3.z), H15 = as_v2h(hv3.w);                   \
        const v2h H16 = as_v2h(hv4.x), H17 = as_v2h(hv4.y);                   \
        const v2h H18 = as_v2h(hv4.z), H19 = as_v2h(hv4.w);                   \
        const v2h H20 = as_v2h(hv5.x), H21 = as_v2h(hv5.y);                   \
        const v2h H22 = as_v2h(hv5.z), H23 = as_v2h(hv5.w);                   \
        const v2h H24 = as_v2h(hv6.x), H25 = as_v2h(hv6.y);                   \
        const v2h H26 = as_v2h(hv6.z), H27 = as_v2h(hv6.w);                   \
        const v2h H28 = as_v2h(hv7.x), H29 = as_v2h(hv7.y);                   \
        const v2h H30 = as_v2h(hv7.z), H31 = as_v2h(hv7.w);                   \
        float zi, zf, zg, zo;                                                 \
        DOTG(0, zcur.x, zi)                                                   \
        DOTG(1, zcur.y, zf)                                                   \
        DOTG(2, zcur.z, zg)                                                   \
        DOTG(3, zcur.w, zo)                                                   \
        const float ai  = sig_f(zi);                                          \
        const float afv = sig_f(zf);                                          \
        const float ag  = tanh_f(zg);                                         \
        const float ao  = sig_f(zo);                                          \
        const float cn = fmaf(afv, c, ai * ag);                               \
        const float hn = ao * tanh_f(cn);                                     \
        if (mskc) { c = cn; hreg = hn; }   /* uniform branch */               \
        s_hh[WP][l] = (_Float16)hreg;                                         \
        zcur = znext; mskc = mskn;                                            \
        stokA = __builtin_amdgcn_readfirstlane(vtokB);                        \
    }

#pragma unroll 1
    for (int t = 0; t < kT; t += 2) {
        STEP(0, 1, t)
        STEP(1, 0, t + 1)
    }
#undef STEP
#undef DOTG

    // ---- epilogue: lane l holds exact f32 h_f[l] and h_b[l] ----
    float v = hreg * Wd[l] + hb_val * Wd[kU + l];
#pragma unroll
    for (int off = 32; off > 0; off >>= 1) v += __shfl_down(v, off, 64);
    if (l == 0) out[b] = v + bd[0];
}

extern "C" void kernel_launch(void* const* d_in, const int* in_sizes, int n_in,
                              void* d_out, int out_size, void* d_ws, size_t ws_size,
                              hipStream_t stream) {
    const int*   tokens = (const int*)d_in[0];
    const float* emb    = (const float*)d_in[1];
    const float* Wk_f   = (const float*)d_in[2];
    const float* Wr_f   = (const float*)d_in[3];
    const float* b_f    = (const float*)d_in[4];
    const float* Wk_b   = (const float*)d_in[5];
    // d_in[6] = Wr_b: unused (backward runs one step from h0=0)
    const float* b_b    = (const float*)d_in[7];
    const float* Wd     = (const float*)d_in[8];
    const float* bd     = (const float*)d_in[9];
    float* out = (float*)d_out;

    bilstm_last_kernel<<<kB, 64, 0, stream>>>(
        tokens, emb, Wk_f, Wr_f, b_f, Wk_b, b_b, Wd, bd, out);
}

// Round 4
// 405.532 us; speedup vs baseline: 1.2633x; 1.1294x over previous
//
#include <hip/hip_runtime.h>

// Bidirectional LSTM, B=256, T=1024, V=6, D=64, U=64; out = last-step
// concat(h_f, h_b) @ Wd + bd, shape (B,1).
// Reductions: backward dir = ONE step from h0=0 (Wr_b dead); V=6 -> xproj is
// a 6-entry table; mask = 6-bit scalar.
// R12 (4 waves, split-K quads + dpp reduce + barrier): 296us.
// R13/R14/R15 (single wave, 128 weight v2h resident): 460/460/400us. RA gave
//   88/88/132 VGPR vs ~185 needed -> persistent scratch spill of weights.
//   Two rounds of fighting the allocator failed; restructure to fit.
// R16: 4 waves, ONE GATE COLUMN PER LANE. 256 columns / 256 threads = 1 full
//   64-len dot per thread: 32 v2h weights = 32 VGPRs (no RA fight), 32 dot2 =
//   64cyc issue per SIMD (4 SIMDs parallel). Wave g owns gate g -> wave-
//   uniform activation. No cross-lane reduce. Per step: one act exchange
//   (4 conflict-free ds_read_b32 from a double-buffered [2][256] table) + ONE
//   __syncthreads. Each wave computes c/h redundantly for all units and
//   round-trips h through its OWN s_hh buffer (same-wave in-order DS -> no
//   barrier for h). Backward step + proj build use the same per-column split.

constexpr int kB = 256;
constexpr int kT = 1024;
constexpr int kV = 6;
constexpr int kD = 64;
constexpr int kU = 64;
constexpr int kG = 256; // 4*U gate columns

#define LOG2E 1.44269504f

typedef _Float16 v2h __attribute__((ext_vector_type(2)));

__device__ __forceinline__ float fast_rcp(float x) { return __builtin_amdgcn_rcpf(x); }
__device__ __forceinline__ float exp2_f(float x)   { return __builtin_amdgcn_exp2f(x); }
__device__ __forceinline__ float sig_f(float z)  { return fast_rcp(1.0f + exp2_f(-LOG2E * z)); }
__device__ __forceinline__ float tanh_f(float z) { return 2.0f * fast_rcp(1.0f + exp2_f(-2.0f * LOG2E * z)) - 1.0f; }

__device__ __forceinline__ v2h as_v2h(float x) { return __builtin_bit_cast(v2h, x); }

__global__ __launch_bounds__(256)
__attribute__((amdgpu_waves_per_eu(1, 1)))
void bilstm_last_kernel(
    const int*   __restrict__ tokens, // (B,T)
    const float* __restrict__ emb,    // (6,64)
    const float* __restrict__ Wk_f,   // (64,256)
    const float* __restrict__ Wr_f,   // (64,256)
    const float* __restrict__ b_f,    // (256)
    const float* __restrict__ Wk_b,   // (64,256)
    const float* __restrict__ b_b,    // (256)
    const float* __restrict__ Wd,     // (128)
    const float* __restrict__ bd,     // (1)
    float*       __restrict__ out)    // (B)
{
    __shared__ float s_emb[kV * kD];
    __shared__ float __align__(16) s_proj[kV * kG];     // [v][col] f32
    __shared__ int   __align__(16) s_tok[kT];
    __shared__ _Float16 __align__(16) s_hh[4][kU];      // PER-WAVE h copy (f16)
    __shared__ float s_act[2][kG];                      // double-buffered acts

    const int b   = blockIdx.x;
    const int tid = threadIdx.x;     // == gate column g*64+l
    const int l   = tid & 63;        // lane = unit id
    const int g   = tid >> 6;        // wave id = gate id (0=i,1=f,2=g,3=o)

    // ---- stage emb + tokens; zero own h buffer ----
    for (int i = tid; i < kV * kD; i += 256) s_emb[i] = emb[i];
    ((int4*)s_tok)[tid] = ((const int4*)(tokens + b * kT))[tid];
    s_hh[g][l] = (_Float16)0.f;
    __syncthreads();   // emb + tokens visible to all waves

    // ---- 6-bit mask (each wave computes identical copy) ----
    unsigned int mbv = 0;
#pragma unroll
    for (int v = 0; v < kV; ++v) {
        const unsigned long long bb = __ballot(s_emb[v * kD + l] != 0.0f);
        mbv |= (bb != 0ull) ? (1u << v) : 0u;
    }
    const unsigned int smb = __builtin_amdgcn_readfirstlane(mbv);

    const int tokL = __builtin_amdgcn_readfirstlane(s_tok[kT - 1]);

    // ---- proj: this thread owns forward column tid for all 6 tokens, plus
    //      the backward column at the last token ----
    float afv[kV];
    float ab;
    {
        const float bf = b_f[tid];
#pragma unroll
        for (int v = 0; v < kV; ++v) afv[v] = bf;
        ab = b_b[tid];
#pragma unroll 4
        for (int d = 0; d < kD; ++d) {
            const float wkf = Wk_f[d * kG + tid];
            const float wkb = Wk_b[d * kG + tid];
            afv[0] = fmaf(s_emb[0 * kD + d], wkf, afv[0]);
            afv[1] = fmaf(s_emb[1 * kD + d], wkf, afv[1]);
            afv[2] = fmaf(s_emb[2 * kD + d], wkf, afv[2]);
            afv[3] = fmaf(s_emb[3 * kD + d], wkf, afv[3]);
            afv[4] = fmaf(s_emb[4 * kD + d], wkf, afv[4]);
            afv[5] = fmaf(s_emb[5 * kD + d], wkf, afv[5]);
            ab     = fmaf(s_emb[tokL * kD + d], wkb, ab);
        }
#pragma unroll
        for (int v = 0; v < kV; ++v) s_proj[v * kG + tid] = afv[v];
    }

    // backward activation for own gate column (wave-uniform act fn)
    {
        const float abact = (g == 2) ? tanh_f(ab) : sig_f(ab);
        s_act[1][tid] = abact;   // buffer 1: free until step t=1 (see proof below)
    }
    __syncthreads();   // proj + backward acts visible

    // ---- backward single step, redundantly per wave (c0=0 -> f dead) ----
    float hb_val;
    {
        const float ib = s_act[1][0 * kU + l];
        const float gb = s_act[1][2 * kU + l];
        const float ob = s_act[1][3 * kU + l];
        const float cb = ib * gb;
        const float hb = ob * tanh_f(cb);
        hb_val = ((smb >> tokL) & 1) ? hb : 0.0f;
    }

    // ---- recurrent weights: own column tid as 32 named f16 pairs ----
#define DECLW(p)                                                              \
    v2h wh_##p;                                                               \
    wh_##p.x = (_Float16)Wr_f[(2 * (p) + 0) * kG + tid];                      \
    wh_##p.y = (_Float16)Wr_f[(2 * (p) + 1) * kG + tid];
    DECLW(0)  DECLW(1)  DECLW(2)  DECLW(3)  DECLW(4)  DECLW(5)  DECLW(6)  DECLW(7)
    DECLW(8)  DECLW(9)  DECLW(10) DECLW(11) DECLW(12) DECLW(13) DECLW(14) DECLW(15)
    DECLW(16) DECLW(17) DECLW(18) DECLW(19) DECLW(20) DECLW(21) DECLW(22) DECLW(23)
    DECLW(24) DECLW(25) DECLW(26) DECLW(27) DECLW(28) DECLW(29) DECLW(30) DECLW(31)
#undef DECLW

    // wave-uniform activation constants (gate 2 = tanh, others sigmoid)
    const float aScale = (g == 2) ? -2.0f * LOG2E : -LOG2E;
    const float aMul   = (g == 2) ? 2.0f : 1.0f;
    const float aAdd   = (g == 2) ? -1.0f : 0.0f;

    float c = 0.0f, hreg = 0.0f;

    // ---- scalar token pipeline, depth 2 ----
    int stok0 = __builtin_amdgcn_readfirstlane(s_tok[0]);
    float zcur = s_proj[stok0 * kG + tid];
    int mskc = (smb >> stok0) & 1;
    int stokA = __builtin_amdgcn_readfirstlane(s_tok[1]);

    // s_act buffer-P race safety: step t reads buffer P after barrier(t);
    // those reads drain before this wave passes barrier(t+1) (__syncthreads
    // waits lgkmcnt(0)); any wave writes buffer P again only at step t+2,
    // i.e. after passing barrier(t+1). Double-buffer + 1 barrier/step is safe.
#define STEP(P, TT)                                                           \
    {                                                                         \
        /* own-wave h copy: broadcast reads, same-wave in-order vs write */   \
        const float4* hp = (const float4*)s_hh[g];                            \
        const float4 hv0 = hp[0], hv1 = hp[1], hv2 = hp[2], hv3 = hp[3];      \
        const float4 hv4 = hp[4], hv5 = hp[5], hv6 = hp[6], hv7 = hp[7];      \
        const int   vtokB = s_tok[((TT) + 2) & (kT - 1)];                     \
        const float znext = s_proj[stokA * kG + tid];                         \
        const int   mskn  = (int)((smb >> stokA) & 1);                        \
        const v2h H0  = as_v2h(hv0.x), H1  = as_v2h(hv0.y);                   \
        const v2h H2  = as_v2h(hv0.z), H3  = as_v2h(hv0.w);                   \
        const v2h H4  = as_v2h(hv1.x), H5  = as_v2h(hv1.y);                   \
        const v2h H6  = as_v2h(hv1.z), H7  = as_v2h(hv1.w);                   \
        const v2h H8  = as_v2h(hv2.x), H9  = as_v2h(hv2.y);                   \
        const v2h H10 = as_v2h(hv2.z), H11 = as_v2h(hv2.w);                   \
        const v2h H12 = as_v2h(hv3.x), H13 = as_v2h(hv3.y);                   \
        const v2h H14 = as_v2h(hv3.z), H15 = as_v2h(hv3.w);                   \
        const v2h H16 = as_v2h(hv4.x), H17 = as_v2h(hv4.y);                   \
        const v2h H18 = as_v2h(hv4.z), H19 = as_v2h(hv4.w);                   \
        const v2h H20 = as_v2h(hv5.x), H21 = as_v2h(hv5.y);                   \
        const v2h H22 = as_v2h(hv5.z), H23 = as_v2h(hv5.w);                   \
        const v2h H24 = as_v2h(hv6.x), H25 = as_v2h(hv6.y);                   \
        const v2h H26 = as_v2h(hv6.z), H27 = as_v2h(hv6.w);                   \
        const v2h H28 = as_v2h(hv7.x), H29 = as_v2h(hv7.y);                   \
        const v2h H30 = as_v2h(hv7.z), H31 = as_v2h(hv7.w);                   \
        /* full 64-len dot for own gate column: 2 chains of depth 16 */       \
        float pa = __builtin_amdgcn_fdot2(H0,  wh_0,  zcur, false);           \
        float pb = __builtin_amdgcn_fdot2(H1,  wh_1,  0.0f, false);           \
        pa = __builtin_amdgcn_fdot2(H2,  wh_2,  pa, false);                   \
        pb = __builtin_amdgcn_fdot2(H3,  wh_3,  pb, false);                   \
        pa = __builtin_amdgcn_fdot2(H4,  wh_4,  pa, false);                   \
        pb = __builtin_amdgcn_fdot2(H5,  wh_5,  pb, false);                   \
        pa = __builtin_amdgcn_fdot2(H6,  wh_6,  pa, false);                   \
        pb = __builtin_amdgcn_fdot2(H7,  wh_7,  pb, false);                   \
        pa = __builtin_amdgcn_fdot2(H8,  wh_8,  pa, false);                   \
        pb = __builtin_amdgcn_fdot2(H9,  wh_9,  pb, false);                   \
        pa = __builtin_amdgcn_fdot2(H10, wh_10, pa, false);                   \
        pb = __builtin_amdgcn_fdot2(H11, wh_11, pb, false);                   \
        pa = __builtin_amdgcn_fdot2(H12, wh_12, pa, false);                   \
        pb = __builtin_amdgcn_fdot2(H13, wh_13, pb, false);                   \
        pa = __builtin_amdgcn_fdot2(H14, wh_14, pa, false);                   \
        pb = __builtin_amdgcn_fdot2(H15, wh_15, pb, false);                   \
        pa = __builtin_amdgcn_fdot2(H16, wh_16, pa, false);                   \
        pb = __builtin_amdgcn_fdot2(H17, wh_17, pb, false);                   \
        pa = __builtin_amdgcn_fdot2(H18, wh_18, pa, false);                   \
        pb = __builtin_amdgcn_fdot2(H19, wh_19, pb, false);                   \
        pa = __builtin_amdgcn_fdot2(H20, wh_20, pa, false);                   \
        pb = __builtin_amdgcn_fdot2(H21, wh_21, pb, false);                   \
        pa = __builtin_amdgcn_fdot2(H22, wh_22, pa, false);                   \
        pb = __builtin_amdgcn_fdot2(H23, wh_23, pb, false);                   \
        pa = __builtin_amdgcn_fdot2(H24, wh_24, pa, false);                   \
        pb = __builtin_amdgcn_fdot2(H25, wh_25, pb, false);                   \
        pa = __builtin_amdgcn_fdot2(H26, wh_26, pa, false);                   \
        pb = __builtin_amdgcn_fdot2(H27, wh_27, pb, false);                   \
        pa = __builtin_amdgcn_fdot2(H28, wh_28, pa, false);                   \
        pb = __builtin_amdgcn_fdot2(H29, wh_29, pb, false);                   \
        pa = __builtin_amdgcn_fdot2(H30, wh_30, pa, false);                   \
        pb = __builtin_amdgcn_fdot2(H31, wh_31, pb, false);                   \
        const float z = pa + pb;                                              \
        /* own-gate activation (wave-uniform constants) */                    \
        const float e = exp2_f(z * aScale);                                   \
        const float r = fast_rcp(1.0f + e);                                   \
        const float a = fmaf(r, aMul, aAdd);                                  \
        s_act[P][tid] = a;                                                    \
        __syncthreads();                                                      \
        const float ai  = s_act[P][0 * kU + l];                               \
        const float af_ = s_act[P][1 * kU + l];                               \
        const float ag  = s_act[P][2 * kU + l];                               \
        const float ao  = s_act[P][3 * kU + l];                               \
        const float cn = fmaf(af_, c, ai * ag);                               \
        const float hn = ao * tanh_f(cn);                                     \
        if (mskc) { c = cn; hreg = hn; }   /* uniform branch */               \
        s_hh[g][l] = (_Float16)hreg;                                          \
        zcur = znext; mskc = mskn;                                            \
        stokA = __builtin_amdgcn_readfirstlane(vtokB);                        \
    }

#pragma unroll 1
    for (int t = 0; t < kT; t += 2) {
        STEP(0, t)
        STEP(1, t + 1)
    }
#undef STEP

    // ---- epilogue: every wave has identical h; wave 0 reduces ----
    if (tid < kU) {
        float v = hreg * Wd[tid] + hb_val * Wd[kU + tid];
#pragma unroll
        for (int off = 32; off > 0; off >>= 1) v += __shfl_down(v, off, 64);
        if (tid == 0) out[b] = v + bd[0];
    }
}

extern "C" void kernel_launch(void* const* d_in, const int* in_sizes, int n_in,
                              void* d_out, int out_size, void* d_ws, size_t ws_size,
                              hipStream_t stream) {
    const int*   tokens = (const int*)d_in[0];
    const float* emb    = (const float*)d_in[1];
    const float* Wk_f   = (const float*)d_in[2];
    const float* Wr_f   = (const float*)d_in[3];
    const float* b_f    = (const float*)d_in[4];
    const float* Wk_b   = (const float*)d_in[5];
    // d_in[6] = Wr_b: unused (backward runs one step from h0=0)
    const float* b_b    = (const float*)d_in[7];
    const float* Wd     = (const float*)d_in[8];
    const float* bd     = (const float*)d_in[9];
    float* out = (float*)d_out;

    bilstm_last_kernel<<<kB, 256, 0, stream>>>(
        tokens, emb, Wk_f, Wr_f, b_f, Wk_b, b_b, Wd, bd, out);
}

// Round 5
// 349.461 us; speedup vs baseline: 1.4660x; 1.1605x over previous
//
#include <hip/hip_runtime.h>

// Bidirectional LSTM, B=256, T=1024, V=6, D=64, U=64; out = last-step
// concat(h_f, h_b) @ Wd + bd, shape (B,1).
// Reductions: backward dir = ONE step from h0=0 (Wr_b dead); V=6 -> xproj is
// a 6-entry table; mask = 6-bit scalar.
// R12 (4 waves, split-K quads + dpp reduce + barrier): 296us.
// R13-R15 (single wave, 128 weight v2h resident): 400-460us, RA spills.
// R16 (4 waves, one column/lane, LDS act exchange): 360us = ~840cyc/step.
//   ~600cyc is latency: TWO LDS round-trips (act write->barrier->read ~180;
//   h write->same-wave read ~130) + 2x16 dep dot chain (~128).
// R17: QUAD-GATE layout. Thread (wv,l): unit u=wv*16+(l>>2), gate s=l&3,
//   full 64-len column (32 v2h = 32 VGPRs, R16-proven). Act exchange now 4
//   quad_perm DPP broadcasts (~10cyc, no LDS, no barrier) - deletes R16's
//   act round-trip. Quad redundantly computes c/h of its unit; lane s==0
//   writes f16 h; ONE barrier; next step broadcast-reads h (8x b128).
//   Dot: 4 independent chains of depth 8 (dep latency 128->~64).
//   Backward-step act exchange also via DPP (s_act array deleted).

constexpr int kB = 256;
constexpr int kT = 1024;
constexpr int kV = 6;
constexpr int kD = 64;
constexpr int kU = 64;
constexpr int kG = 256; // 4*U gate columns

#define LOG2E 1.44269504f

typedef _Float16 v2h __attribute__((ext_vector_type(2)));

template <int CTRL>
__device__ __forceinline__ float dppf(float x) {
    return __int_as_float(
        __builtin_amdgcn_mov_dpp(__float_as_int(x), CTRL, 0xF, 0xF, true));
}
constexpr int kBc0 = 0x00, kBc1 = 0x55, kBc2 = 0xAA, kBc3 = 0xFF; // quad bcast

__device__ __forceinline__ float fast_rcp(float x) { return __builtin_amdgcn_rcpf(x); }
__device__ __forceinline__ float exp2_f(float x)   { return __builtin_amdgcn_exp2f(x); }
__device__ __forceinline__ float sig_f(float z)  { return fast_rcp(1.0f + exp2_f(-LOG2E * z)); }
__device__ __forceinline__ float tanh_f(float z) { return 2.0f * fast_rcp(1.0f + exp2_f(-2.0f * LOG2E * z)) - 1.0f; }

__device__ __forceinline__ v2h as_v2h(float x) { return __builtin_bit_cast(v2h, x); }

__global__ __launch_bounds__(256)
__attribute__((amdgpu_waves_per_eu(1, 1)))
void bilstm_last_kernel(
    const int*   __restrict__ tokens, // (B,T)
    const float* __restrict__ emb,    // (6,64)
    const float* __restrict__ Wk_f,   // (64,256)
    const float* __restrict__ Wr_f,   // (64,256)
    const float* __restrict__ b_f,    // (256)
    const float* __restrict__ Wk_b,   // (64,256)
    const float* __restrict__ b_b,    // (256)
    const float* __restrict__ Wd,     // (128)
    const float* __restrict__ bd,     // (1)
    float*       __restrict__ out)    // (B)
{
    __shared__ float s_emb[kV * kD];
    __shared__ float __align__(16) s_projP[kV * kG];    // [v][tid] (perm by tid)
    __shared__ int   __align__(16) s_tok[kT];
    __shared__ _Float16 __align__(16) s_hh[2][kU];      // double-buffered h (f16)
    __shared__ float s_red[4];                          // epilogue partials

    const int b   = blockIdx.x;
    const int tid = threadIdx.x;
    const int l   = tid & 63;        // lane in wave
    const int wv  = tid >> 6;        // wave id
    const int s   = l & 3;           // gate (0=i,1=f,2=g,3=o)
    const int k   = l >> 2;          // quad id 0..15
    const int u   = wv * 16 + k;     // unit owned by this quad
    const int col = s * kU + u;      // owned gate column in (.,256) matrices

    // ---- stage emb + tokens; zero h buffers ----
    for (int i = tid; i < kV * kD; i += 256) s_emb[i] = emb[i];
    ((int4*)s_tok)[tid] = ((const int4*)(tokens + b * kT))[tid];
    if (tid < 2 * kU) ((_Float16*)s_hh)[tid] = (_Float16)0.f;
    __syncthreads();   // emb + tokens visible

    // ---- 6-bit mask, scalarized: bit v = any(emb[v][:] != 0) ----
    unsigned int mbv = 0;
#pragma unroll
    for (int v = 0; v < kV; ++v) {
        const unsigned long long bb = __ballot(s_emb[v * kD + l] != 0.0f);
        mbv |= (bb != 0ull) ? (1u << v) : 0u;
    }
    const unsigned int smb = __builtin_amdgcn_readfirstlane(mbv);

    const int tokL = __builtin_amdgcn_readfirstlane(s_tok[kT - 1]);

    // ---- proj: own forward column for all 6 tokens (stored permuted by tid
    //      -> step reads are stride-1, conflict-free), + backward column ----
    float ab;
    {
        float afv[kV];
        const float bf = b_f[col];
#pragma unroll
        for (int v = 0; v < kV; ++v) afv[v] = bf;
        ab = b_b[col];
#pragma unroll 4
        for (int d = 0; d < kD; ++d) {
            const float wkf = Wk_f[d * kG + col];
            const float wkb = Wk_b[d * kG + col];
            afv[0] = fmaf(s_emb[0 * kD + d], wkf, afv[0]);
            afv[1] = fmaf(s_emb[1 * kD + d], wkf, afv[1]);
            afv[2] = fmaf(s_emb[2 * kD + d], wkf, afv[2]);
            afv[3] = fmaf(s_emb[3 * kD + d], wkf, afv[3]);
            afv[4] = fmaf(s_emb[4 * kD + d], wkf, afv[4]);
            afv[5] = fmaf(s_emb[5 * kD + d], wkf, afv[5]);
            ab     = fmaf(s_emb[tokL * kD + d], wkb, ab);
        }
#pragma unroll
        for (int v = 0; v < kV; ++v) s_projP[v * kG + tid] = afv[v];
    }

    // per-lane activation constants: gate s==2 is tanh, others sigmoid
    const bool  isg    = (s == 2);
    const float aScale = isg ? -2.0f * LOG2E : -LOG2E;
    const float aMul   = isg ? 2.0f : 1.0f;
    const float aAdd   = isg ? -1.0f : 0.0f;

    // ---- backward single step via quad DPP (c0=0 -> f dead) ----
    float hb_val;
    {
        const float e = exp2_f(ab * aScale);
        const float r = fast_rcp(1.0f + e);
        const float a = fmaf(r, aMul, aAdd);
        const float ib = dppf<kBc0>(a);
        const float gb = dppf<kBc2>(a);
        const float ob = dppf<kBc3>(a);
        const float cb = ib * gb;
        const float hb = ob * tanh_f(cb);
        hb_val = ((smb >> tokL) & 1) ? hb : 0.0f;
    }

    // ---- recurrent weights: own column col as 32 named f16 pairs ----
#define DECLW(p)                                                              \
    v2h wh_##p;                                                               \
    wh_##p.x = (_Float16)Wr_f[(2 * (p) + 0) * kG + col];                      \
    wh_##p.y = (_Float16)Wr_f[(2 * (p) + 1) * kG + col];
    DECLW(0)  DECLW(1)  DECLW(2)  DECLW(3)  DECLW(4)  DECLW(5)  DECLW(6)  DECLW(7)
    DECLW(8)  DECLW(9)  DECLW(10) DECLW(11) DECLW(12) DECLW(13) DECLW(14) DECLW(15)
    DECLW(16) DECLW(17) DECLW(18) DECLW(19) DECLW(20) DECLW(21) DECLW(22) DECLW(23)
    DECLW(24) DECLW(25) DECLW(26) DECLW(27) DECLW(28) DECLW(29) DECLW(30) DECLW(31)
#undef DECLW

    float c = 0.0f, hreg = 0.0f;

    // ---- scalar token pipeline, depth 2 ----
    int stok0 = __builtin_amdgcn_readfirstlane(s_tok[0]);
    float zcur = s_projP[stok0 * kG + tid];
    int mskc = (smb >> stok0) & 1;
    int stokA = __builtin_amdgcn_readfirstlane(s_tok[1]);

    // h-buffer safety: step t reads s_hh[RP] before its barrier (reads drain
    // at the barrier's lgkmcnt(0)); buffer RP is rewritten only in step t+1
    // after that barrier. Double-buffer + 1 barrier/step is safe.
#define STEP(RP, WP, TT)                                                      \
    {                                                                         \
        const float4* hp = (const float4*)s_hh[RP];                           \
        const float4 hv0 = hp[0], hv1 = hp[1], hv2 = hp[2], hv3 = hp[3];      \
        const float4 hv4 = hp[4], hv5 = hp[5], hv6 = hp[6], hv7 = hp[7];      \
        /* prefetches queued behind h; consumed next step */                  \
        const int   vtokB = s_tok[((TT) + 2) & (kT - 1)];                     \
        const float znext = s_projP[stokA * kG + tid];                        \
        const int   mskn  = (int)((smb >> stokA) & 1);                        \
        const v2h H0  = as_v2h(hv0.x), H1  = as_v2h(hv0.y);                   \
        const v2h H2  = as_v2h(hv0.z), H3  = as_v2h(hv0.w);                   \
        const v2h H4  = as_v2h(hv1.x), H5  = as_v2h(hv1.y);                   \
        const v2h H6  = as_v2h(hv1.z), H7  = as_v2h(hv1.w);                   \
        const v2h H8  = as_v2h(hv2.x), H9  = as_v2h(hv2.y);                   \
        const v2h H10 = as_v2h(hv2.z), H11 = as_v2h(hv2.w);                   \
        const v2h H12 = as_v2h(hv3.x), H13 = as_v2h(hv3.y);                   \
        const v2h H14 = as_v2h(hv3.z), H15 = as_v2h(hv3.w);                   \
        const v2h H16 = as_v2h(hv4.x), H17 = as_v2h(hv4.y);                   \
        const v2h H18 = as_v2h(hv4.z), H19 = as_v2h(hv4.w);                   \
        const v2h H20 = as_v2h(hv5.x), H21 = as_v2h(hv5.y);                   \
        const v2h H22 = as_v2h(hv5.z), H23 = as_v2h(hv5.w);                   \
        const v2h H24 = as_v2h(hv6.x), H25 = as_v2h(hv6.y);                   \
        const v2h H26 = as_v2h(hv6.z), H27 = as_v2h(hv6.w);                   \
        const v2h H28 = as_v2h(hv7.x), H29 = as_v2h(hv7.y);                   \
        const v2h H30 = as_v2h(hv7.z), H31 = as_v2h(hv7.w);                   \
        /* full 64-len dot: 4 independent chains of depth 8 */                \
        float pa = __builtin_amdgcn_fdot2(H0,  wh_0,  zcur, false);           \
        float pb = __builtin_amdgcn_fdot2(H1,  wh_1,  0.0f, false);           \
        float pc = __builtin_amdgcn_fdot2(H2,  wh_2,  0.0f, false);           \
        float pd = __builtin_amdgcn_fdot2(H3,  wh_3,  0.0f, false);           \
        pa = __builtin_amdgcn_fdot2(H4,  wh_4,  pa, false);                   \
        pb = __builtin_amdgcn_fdot2(H5,  wh_5,  pb, false);                   \
        pc = __builtin_amdgcn_fdot2(H6,  wh_6,  pc, false);                   \
        pd = __builtin_amdgcn_fdot2(H7,  wh_7,  pd, false);                   \
        pa = __builtin_amdgcn_fdot2(H8,  wh_8,  pa, false);                   \
        pb = __builtin_amdgcn_fdot2(H9,  wh_9,  pb, false);                   \
        pc = __builtin_amdgcn_fdot2(H10, wh_10, pc, false);                   \
        pd = __builtin_amdgcn_fdot2(H11, wh_11, pd, false);                   \
        pa = __builtin_amdgcn_fdot2(H12, wh_12, pa, false);                   \
        pb = __builtin_amdgcn_fdot2(H13, wh_13, pb, false);                   \
        pc = __builtin_amdgcn_fdot2(H14, wh_14, pc, false);                   \
        pd = __builtin_amdgcn_fdot2(H15, wh_15, pd, false);                   \
        pa = __builtin_amdgcn_fdot2(H16, wh_16, pa, false);                   \
        pb = __builtin_amdgcn_fdot2(H17, wh_17, pb, false);                   \
        pc = __builtin_amdgcn_fdot2(H18, wh_18, pc, false);                   \
        pd = __builtin_amdgcn_fdot2(H19, wh_19, pd, false);                   \
        pa = __builtin_amdgcn_fdot2(H20, wh_20, pa, false);                   \
        pb = __builtin_amdgcn_fdot2(H21, wh_21, pb, false);                   \
        pc = __builtin_amdgcn_fdot2(H22, wh_22, pc, false);                   \
        pd = __builtin_amdgcn_fdot2(H23, wh_23, pd, false);                   \
        pa = __builtin_amdgcn_fdot2(H24, wh_24, pa, false);                   \
        pb = __builtin_amdgcn_fdot2(H25, wh_25, pb, false);                   \
        pc = __builtin_amdgcn_fdot2(H26, wh_26, pc, false);                   \
        pd = __builtin_amdgcn_fdot2(H27, wh_27, pd, false);                   \
        pa = __builtin_amdgcn_fdot2(H28, wh_28, pa, false);                   \
        pb = __builtin_amdgcn_fdot2(H29, wh_29, pb, false);                   \
        pc = __builtin_amdgcn_fdot2(H30, wh_30, pc, false);                   \
        pd = __builtin_amdgcn_fdot2(H31, wh_31, pd, false);                   \
        const float z = (pa + pb) + (pc + pd);                                \
        /* own-gate activation (per-lane constants) */                        \
        const float e = exp2_f(z * aScale);                                   \
        const float r = fast_rcp(1.0f + e);                                   \
        const float a = fmaf(r, aMul, aAdd);                                  \
        /* quad DPP broadcast: gate q lives in lane q of the quad */          \
        const float ai = dppf<kBc0>(a);                                       \
        const float af = dppf<kBc1>(a);                                       \
        const float ag = dppf<kBc2>(a);                                       \
        const float ao = dppf<kBc3>(a);                                       \
        const float cn = fmaf(af, c, ai * ag);                                \
        const float hn = ao * tanh_f(cn);                                     \
        if (mskc) { c = cn; hreg = hn; }   /* uniform branch */               \
        if (s == 0) s_hh[WP][u] = (_Float16)hreg;                             \
        __syncthreads();                                                      \
        zcur = znext; mskc = mskn;                                            \
        stokA = __builtin_amdgcn_readfirstlane(vtokB);                        \
    }

#pragma unroll 1
    for (int t = 0; t < kT; t += 2) {
        STEP(0, 1, t)
        STEP(1, 0, t + 1)
    }
#undef STEP

    // ---- epilogue: quad lane s==0 holds exact f32 h_f[u], h_b[u] ----
    {
        float v = (s == 0) ? (hreg * Wd[u] + hb_val * Wd[kU + u]) : 0.0f;
#pragma unroll
        for (int off = 32; off > 0; off >>= 1) v += __shfl_down(v, off, 64);
        if (l == 0) s_red[wv] = v;
    }
    __syncthreads();
    if (tid == 0) out[b] = (s_red[0] + s_red[1]) + (s_red[2] + s_red[3]) + bd[0];
}

extern "C" void kernel_launch(void* const* d_in, const int* in_sizes, int n_in,
                              void* d_out, int out_size, void* d_ws, size_t ws_size,
                              hipStream_t stream) {
    const int*   tokens = (const int*)d_in[0];
    const float* emb    = (const float*)d_in[1];
    const float* Wk_f   = (const float*)d_in[2];
    const float* Wr_f   = (const float*)d_in[3];
    const float* b_f    = (const float*)d_in[4];
    const float* Wk_b   = (const float*)d_in[5];
    // d_in[6] = Wr_b: unused (backward runs one step from h0=0)
    const float* b_b    = (const float*)d_in[7];
    const float* Wd     = (const float*)d_in[8];
    const float* bd     = (const float*)d_in[9];
    float* out = (float*)d_out;

    bilstm_last_kernel<<<kB, 256, 0, stream>>>(
        tokens, emb, Wk_f, Wr_f, b_f, Wk_b, b_b, Wd, bd, out);
}